// Round 11
// baseline (1264.521 us; speedup 1.0000x reference)
//
#include <hip/hip_runtime.h>
#include <hip/hip_bf16.h>
#include <cstdint>
#include <cstddef>

#define B_   32
#define L_   12
#define N_   883
#define DM_  64
#define E_SP 14128
#define E_TP 144
#define NT_  12
#define RBN  28256      // B*N
#define RBL  384        // B*L
#define LDM  768        // L*DM
#define NDM  56512      // N*DM

static inline int cdiv_h(int a, int b){ return (a+b-1)/b; }

// bf16 round-to-nearest-even from float
__device__ __forceinline__ ushort f2bf(float f){
    unsigned u = __float_as_uint(f);
    unsigned lsb = (u >> 16) & 1u;
    u += 0x7fffu + lsb;
    return (ushort)(u >> 16);
}
__device__ __forceinline__ float bf2f(ushort h){
    return __uint_as_float(((unsigned)h) << 16);
}
// fp16 RNE from float (v_cvt_f16_f32)
__device__ __forceinline__ ushort f2h(float f){
    _Float16 h = (_Float16)f;
    ushort r; __builtin_memcpy(&r, &h, 2);
    return r;
}

typedef __bf16 bf16x8 __attribute__((ext_vector_type(8)));
typedef _Float16 f16x8 __attribute__((ext_vector_type(8)));
typedef _Float16 f16x2 __attribute__((ext_vector_type(2)));
typedef float  f32x4  __attribute__((ext_vector_type(4)));
typedef short  s16x2  __attribute__((ext_vector_type(2)));
union BF8 { bf16x8 v; ushort u[8]; unsigned w[4]; int4 i; };
union HF8 { f16x8 v; ushort u[8]; unsigned w[4]; int4 i; };

// packed relu on 2 half-precision values (sign-magnitude => signed-i16 max-with-0 is exact relu)
__device__ __forceinline__ unsigned pkrelu(unsigned x){
    s16x2 v;
    __builtin_memcpy(&v, &x, 4);
    s16x2 z = 0;
    v = __builtin_elementwise_max(v, z);
    unsigned r;
    __builtin_memcpy(&r, &v, 4);
    return r;
}
// packed f16 add (v_pk_add_f16): 1 VALU for 2 elements
__device__ __forceinline__ unsigned pkaddh(unsigned x, unsigned y){
    f16x2 a, b;
    __builtin_memcpy(&a, &x, 4);
    __builtin_memcpy(&b, &y, 4);
    a = a + b;
    unsigned r;
    __builtin_memcpy(&r, &a, 4);
    return r;
}

// ========== front-chain collapse (R5/R6) ==========
__global__ void k_mkA(const float* __restrict__ sw, const float* __restrict__ sb,
                      const float* __restrict__ tsw, const float* __restrict__ tsb,
                      const float* __restrict__ trsp, const float* __restrict__ trspb,
                      float* __restrict__ A1, float* __restrict__ A2,
                      float* __restrict__ cb1, float* __restrict__ cb2)
{
    int idx = blockIdx.x*256 + threadIdx.x;
    if (idx < 36*64) {
        int k = idx >> 6, h = idx & 63;
        int l = k/3, c = k - l*3;
        float s = 0.f;
        #pragma unroll 8
        for (int d = 0; d < 64; ++d) s += sw[c*64+d]*tsw[(size_t)(l*64+d)*64 + h];
        A1[idx] = s;
    } else if (idx < 36*64 + 36*128) {
        int i = idx - 36*64;
        int k = i >> 7, p = i & 127;
        int l = k/3, c = k - l*3;
        float s = 0.f;
        #pragma unroll 8
        for (int d = 0; d < 64; ++d) s += sw[c*64+d]*trsp[(size_t)(l*64+d)*128 + p];
        A2[i] = s;
    } else if (idx < 36*64 + 36*128 + 64) {
        int h = idx - (36*64 + 36*128);
        float s = tsb[h];
        #pragma unroll 8
        for (int k = 0; k < 768; ++k) s += sb[k & 63]*tsw[(size_t)k*64 + h];
        cb1[h] = s;
    } else if (idx < 36*64 + 36*128 + 64 + 128) {
        int p = idx - (36*64 + 36*128 + 64);
        float s = trspb[p];
        #pragma unroll 8
        for (int k = 0; k < 768; ++k) s += sb[k & 63]*trsp[(size_t)k*128 + p];
        cb2[p] = s;
    }
}
// one thread per (bn, h), h in [0,192): h<64 -> ts_res fp32, else spa_in bf16.
__global__ void k_front(const float* __restrict__ hist, const float* __restrict__ A1,
                        const float* __restrict__ A2, const float* __restrict__ cb1,
                        const float* __restrict__ cb2, float* __restrict__ ts_res,
                        ushort* __restrict__ spa_in)
{
    int idx = blockIdx.x*256 + threadIdx.x;
    if (idx >= RBN*192) return;
    int bn = idx / 192, h = idx - bn*192;
    int b = bn / N_, n = bn - b*N_;
    const float* hp = hist + ((size_t)(b*L_)*N_ + n)*3;   // + l*2649 per lag
    bool isTs = (h < 64);
    int hh = isTs ? h : (h - 64);
    int stride = isTs ? 64 : 128;
    const float* A = isTs ? (A1 + hh) : (A2 + hh);
    float acc = isTs ? cb1[hh] : cb2[hh];
    #pragma unroll
    for (int l = 0; l < 12; ++l) {
        float x0 = hp[l*2649 + 0];
        float x1 = hp[l*2649 + 1];
        float x2 = hp[l*2649 + 2];
        acc += x0*A[(l*3+0)*stride] + x1*A[(l*3+1)*stride] + x2*A[(l*3+2)*stride];
    }
    if (isTs) ts_res[(size_t)bn*64 + hh] = acc;
    else      spa_in[(size_t)bn*128 + hh] = f2bf(acc);
}

// ============== generalized MFMA GEMM (direct-from-global), 1 row-tile/wave ==============
template<int CT, int AMODE, int EPI, bool RELU, bool RES>
__launch_bounds__(256)
__global__ void mgemm(const ushort* __restrict__ A, const ushort* __restrict__ WT,
                      const float* __restrict__ bias, float* __restrict__ resF,
                      void* __restrict__ outP, int M, int N, int K)
{
    const int t = threadIdx.x, wv = t >> 6, l = t & 63;
    const int lr = l & 15, lk = l >> 4;
    const int row0 = blockIdx.y*64 + wv*16;
    const int col0 = blockIdx.x * (CT*16);
    int arr = row0 + lr; if (arr >= M) arr = M-1;
    int ab = 0, an = 0;
    if (AMODE == 1) { ab = arr / N_; an = arr - ab*N_; }
    const ushort* ap = A + (size_t)arr*K + lk*8;
    f32x4 acc[CT] = {};
    for (int k0 = 0; k0 < K; k0 += 32) {
        BF8 af;
        if (AMODE == 0) af.i = *(const int4*)(ap + k0);
        else {
            int k = k0 + lk*8; int ll = k >> 6, d = k & 63;
            af.i = *(const int4*)(A + ((size_t)(ab*L_ + ll))*NDM + (size_t)an*64 + d);
        }
        #pragma unroll
        for (int ct = 0; ct < CT; ++ct) {
            BF8 bf; bf.i = *(const int4*)&WT[(size_t)(col0 + ct*16 + lr)*K + k0 + lk*8];
            acc[ct] = __builtin_amdgcn_mfma_f32_16x16x32_bf16(af.v, bf.v, acc[ct], 0, 0, 0);
        }
    }
    #pragma unroll
    for (int ct = 0; ct < CT; ++ct) {
        int c = col0 + ct*16 + lr;
        float bv = 0.f;
        if (EPI == 2) { if (bias && c < 12) bv = bias[c]; }
        else if (bias) bv = bias[c];
        #pragma unroll
        for (int g = 0; g < 4; ++g) {
            int r = row0 + lk*4 + g;
            if (r >= M) continue;
            float v = acc[ct][g] + bv;
            if (RELU) v = fmaxf(v, 0.f);
            if (RES) {
                v += resF[(size_t)r*N + c];
                resF[(size_t)r*N + c] = v;
            }
            if (EPI == 0) {
                ((ushort*)outP)[(size_t)r*N + c] = f2bf(v);
            } else if (EPI == 1) {
                ((float*)outP)[(size_t)r*N + c] = v;
            } else if (EPI == 2) {
                if (c < 12) {
                    int b = r / N_, n = r - (r/N_)*N_;
                    ((float*)outP)[((size_t)(b*L_ + c))*N_ + n] = v;
                }
            } else {
                int b = r / N_, n = r - (r/N_)*N_;
                ((ushort*)outP)[((size_t)(b*L_ + (c>>6)))*NDM + (size_t)n*64 + (c&63)] = f2bf(v);
            }
        }
    }
}

// ============== MFMA GEMM with RT row-tiles/wave (B-load amortization) ==============
// EPI 4: f16 out[r*N+c] (for the extractor PQ buffers consumed by ext2_mfma's packed-f16 path).
template<int RT, int CT, int EPI, bool RELU, bool RES>
__launch_bounds__(256)
__global__ void mgemm_rt(const ushort* __restrict__ A, const ushort* __restrict__ WT,
                         const float* __restrict__ bias, float* __restrict__ resF,
                         void* __restrict__ outP, int M, int N, int K)
{
    const int t = threadIdx.x, wv = t >> 6, l = t & 63;
    const int lr = l & 15, lk = l >> 4;
    const int rowbase = blockIdx.y*(4*RT*16) + wv*(RT*16);
    const int col0 = blockIdx.x * (CT*16);
    const ushort* ap[RT];
    #pragma unroll
    for (int rt = 0; rt < RT; ++rt) {
        int arr = rowbase + rt*16 + lr; if (arr >= M) arr = M-1;
        ap[rt] = A + (size_t)arr*K + lk*8;
    }
    f32x4 acc[RT][CT] = {};
    for (int k0 = 0; k0 < K; k0 += 32) {
        BF8 af[RT];
        #pragma unroll
        for (int rt = 0; rt < RT; ++rt) af[rt].i = *(const int4*)(ap[rt] + k0);
        #pragma unroll
        for (int ct = 0; ct < CT; ++ct) {
            BF8 bf; bf.i = *(const int4*)&WT[(size_t)(col0 + ct*16 + lr)*K + k0 + lk*8];
            #pragma unroll
            for (int rt = 0; rt < RT; ++rt)
                acc[rt][ct] = __builtin_amdgcn_mfma_f32_16x16x32_bf16(af[rt].v, bf.v,
                                                                     acc[rt][ct], 0, 0, 0);
        }
    }
    #pragma unroll
    for (int rt = 0; rt < RT; ++rt)
        #pragma unroll
        for (int ct = 0; ct < CT; ++ct) {
            int c = col0 + ct*16 + lr;
            float bv = bias ? bias[c] : 0.f;
            #pragma unroll
            for (int g = 0; g < 4; ++g) {
                int r = rowbase + rt*16 + lk*4 + g;
                if (r >= M) continue;
                float v = acc[rt][ct][g] + bv;
                if (RELU) v = fmaxf(v, 0.f);
                if (RES) {
                    v += resF[(size_t)r*N + c];
                    resF[(size_t)r*N + c] = v;
                }
                if (EPI == 0) {
                    ((ushort*)outP)[(size_t)r*N + c] = f2bf(v);
                } else if (EPI == 1) {
                    ((float*)outP)[(size_t)r*N + c] = v;
                } else if (EPI == 4) {
                    ((ushort*)outP)[(size_t)r*N + c] = f2h(v);
                } else {  // EPI 3: bf16 AT scatter
                    int b = r / N_, n = r - (r/N_)*N_;
                    ((ushort*)outP)[((size_t)(b*L_ + (c>>6)))*NDM + (size_t)n*64 + (c&63)] = f2bf(v);
                }
            }
        }
}

// ======== fused spatial back-projection + temporal input (R8) ========
#define TNC 8
__launch_bounds__(256)
__global__ void k_tempIn(const ushort* __restrict__ spaB, const ushort* __restrict__ ispWT,
                         const float* __restrict__ isb, const ushort* __restrict__ WtT,
                         float* __restrict__ out)
{
    __shared__ ushort T1[16*768];   // [b_local][(l*64+d) swizzled], bf16, 24KB
    const int t = threadIdx.x, wv = t >> 6, l = t & 63;
    const int lr = l & 15, lk = l >> 4;
    const int bh = blockIdx.y;                 // b-half: b = bh*16 + b_local
    const int n0 = blockIdx.x * TNC;
    const int nEnd = (n0 + TNC < N_) ? n0 + TNC : N_;

    f32x4 acc2[3][8] = {};
    for (int n = n0; n < nEnd; ++n) {
        // ---- stage 1 (reads global only; safe before barrier)
        f32x4 acc1[12] = {};
        for (int k0 = 0; k0 < 128; k0 += 32) {
            BF8 af; af.i = *(const int4*)&spaB[((size_t)(bh*16 + lr)*N_ + n)*128 + k0 + lk*8];
            #pragma unroll
            for (int ct = 0; ct < 12; ++ct) {
                BF8 bf; bf.i = *(const int4*)&ispWT[(size_t)(wv*192 + ct*16 + lr)*128 + k0 + lk*8];
                acc1[ct] = __builtin_amdgcn_mfma_f32_16x16x32_bf16(af.v, bf.v, acc1[ct], 0, 0, 0);
            }
        }
        __syncthreads();   // prev node's stage-2 reads done before overwriting T1
        #pragma unroll
        for (int ct = 0; ct < 12; ++ct) {
            int c = wv*192 + ct*16 + lr;       // (l*64+d)
            float bv = isb[c];
            int ll = c >> 6, d = c & 63;
            #pragma unroll
            for (int g = 0; g < 4; ++g) {
                int b = lk*4 + g;              // local b 0..15
                int r = b*12 + ll;
                T1[b*768 + ll*64 + (d ^ ((r & 7) << 3))] = f2bf(acc1[ct][g] + bv);
            }
        }
        __syncthreads();
        // ---- stage 2: acc2 += T1[192][64] @ Wt_n
        #pragma unroll
        for (int kc = 0; kc < 2; ++kc) {
            BF8 bfr[8];
            #pragma unroll
            for (int ct = 0; ct < 8; ++ct)
                bfr[ct].i = *(const int4*)&WtT[(size_t)(ct*16 + lr)*NDM + (size_t)n*64 + kc*32 + lk*8];
            #pragma unroll
            for (int rt = 0; rt < 3; ++rt) {
                int r = wv*48 + rt*16 + lr;    // local row (b_local*12 + l), 0..191
                int b = r / 12, ll = r - b*12;
                int k = kc*32 + lk*8;
                BF8 af;
                af.v = *(const bf16x8*)&T1[b*768 + ll*64 + (k ^ ((r & 7) << 3))];
                #pragma unroll
                for (int ct = 0; ct < 8; ++ct)
                    acc2[rt][ct] = __builtin_amdgcn_mfma_f32_16x16x32_bf16(af.v, bfr[ct].v,
                                                                          acc2[rt][ct], 0, 0, 0);
            }
        }
    }
    #pragma unroll
    for (int rt = 0; rt < 3; ++rt)
        #pragma unroll
        for (int ct = 0; ct < 8; ++ct) {
            int p = ct*16 + lr;
            #pragma unroll
            for (int g = 0; g < 4; ++g) {
                int r = bh*192 + wv*48 + rt*16 + lk*4 + g;
                atomicAdd(&out[(size_t)r*128 + p], acc2[rt][ct][g]);
            }
        }
}

// ======== fused temporal back-projection + ts_temp (R7, proven) ========
__launch_bounds__(256)
__global__ void k_tsTemp(const ushort* __restrict__ toutB, const ushort* __restrict__ itWT,
                         const float* __restrict__ itb, const ushort* __restrict__ tswT,
                         const float* __restrict__ tsb, float* __restrict__ ts_temp)
{
    __shared__ ushort sb[384*72];   // row (b*12+l), 64 d + 8 pad, bf16
    const int n = blockIdx.x;
    const int t = threadIdx.x, wv = t >> 6, l = t & 63;
    const int lr = l & 15, lk = l >> 4;
    // ---- stage 1: wave wv -> rows wv*96..+95 (6 RT), cols 0..63 (4 CT), K=128 (4 kc)
    {
        f32x4 acc1[6][4] = {};
        for (int k0 = 0; k0 < 128; k0 += 32) {
            BF8 bfr[4];
            #pragma unroll
            for (int ct = 0; ct < 4; ++ct)
                bfr[ct].i = *(const int4*)&itWT[(size_t)(n*64 + ct*16 + lr)*128 + k0 + lk*8];
            #pragma unroll
            for (int rt = 0; rt < 6; ++rt) {
                BF8 af; af.i = *(const int4*)&toutB[(size_t)(wv*96 + rt*16 + lr)*128 + k0 + lk*8];
                #pragma unroll
                for (int ct = 0; ct < 4; ++ct)
                    acc1[rt][ct] = __builtin_amdgcn_mfma_f32_16x16x32_bf16(af.v, bfr[ct].v,
                                                                          acc1[rt][ct], 0, 0, 0);
            }
        }
        #pragma unroll
        for (int rt = 0; rt < 6; ++rt)
            #pragma unroll
            for (int ct = 0; ct < 4; ++ct) {
                int d = ct*16 + lr;
                float bv = itb[n*64 + d];
                #pragma unroll
                for (int g = 0; g < 4; ++g) {
                    int r = wv*96 + rt*16 + lk*4 + g;   // (b*12+l)
                    int bb = r / 12;
                    sb[r*72 + (d ^ ((bb & 7) << 3))] = f2bf(acc1[rt][ct][g] + bv);
                }
            }
    }
    __syncthreads();
    // ---- stage 2: wave wv -> cols wv*16..+15 (1 CT), rows 0..31 (2 RT), K=768 (24 kc)
    f32x4 acc2[2] = {};
    #pragma unroll 2
    for (int j = 0; j < 24; ++j) {
        BF8 bfm; bfm.i = *(const int4*)&tswT[(size_t)(wv*16 + lr)*768 + j*32 + lk*8];
        int lidx = j >> 1;
        int koff = (j & 1)*32 + lk*8;
        #pragma unroll
        for (int rt = 0; rt < 2; ++rt) {
            int bb = rt*16 + lr;
            BF8 af;
            af.v = *(const bf16x8*)&sb[(bb*12 + lidx)*72 + (koff ^ ((bb & 7) << 3))];
            acc2[rt] = __builtin_amdgcn_mfma_f32_16x16x32_bf16(af.v, bfm.v, acc2[rt], 0, 0, 0);
        }
    }
    {
        int h = wv*16 + lr;
        float bv = tsb[h];
        #pragma unroll
        for (int rt = 0; rt < 2; ++rt)
            #pragma unroll
            for (int g = 0; g < 4; ++g) {
                int bb = rt*16 + lk*4 + g;
                ts_temp[((size_t)bb*N_ + n)*64 + h] = acc2[rt][g] + bv;
            }
    }
}

// ============================ attention scores (R9: vectorized, 16 lanes/row) ============
__global__ void k_sc(const ushort* __restrict__ h, const float* __restrict__ as_,
                     const float* __restrict__ ad_, float* __restrict__ scs,
                     float* __restrict__ scd, int R)
{
    int wid = blockIdx.x*4 + (threadIdx.x >> 6);
    int l = threadIdx.x & 63;
    int sub = l >> 4;          // 4 rows per wave
    int j = l & 15;            // 16 lanes per row
    int r = wid*4 + sub;
    if (r >= R) r = R - 1;     // duplicate work on tail, benign
    BF8 hv; hv.i = *(const int4*)&h[(size_t)r*128 + j*8];
    int hh = j >> 2;
    const float* pa = as_ + hh*32 + (j & 3)*8;
    const float* pd = ad_ + hh*32 + (j & 3)*8;
    float ss = 0.f, sd = 0.f;
    #pragma unroll
    for (int k = 0; k < 8; ++k) {
        float x = bf2f(hv.u[k]);
        ss += x*pa[k];
        sd += x*pd[k];
    }
    ss += __shfl_xor(ss, 1, 64); ss += __shfl_xor(ss, 2, 64);
    sd += __shfl_xor(sd, 1, 64); sd += __shfl_xor(sd, 2, 64);
    if ((j & 3) == 0) {
        scs[(size_t)r*4 + hh] = ss;
        scd[(size_t)r*4 + hh] = sd;
    }
}

// ============================ CSR build (target-indexed) ============================
__global__ void k_count(const int* __restrict__ ei, int E, int* __restrict__ counts){
    int e = blockIdx.x*256 + threadIdx.x;
    if (e < E) atomicAdd(&counts[ei[E + e]], 1);
}
__global__ void k_scan(const int* __restrict__ counts, int* __restrict__ off,
                       int* __restrict__ cur, int n)
{
    __shared__ int s[1024];
    int t = threadIdx.x;
    int v0 = (t < n) ? counts[t] : 0;
    s[t] = v0;
    __syncthreads();
    for (int o = 1; o < 1024; o <<= 1) {
        int v = (t >= o) ? s[t-o] : 0;
        __syncthreads();
        s[t] += v;
        __syncthreads();
    }
    if (t < n) {
        off[t+1] = s[t];
        cur[t] = s[t] - v0;
        if (t == 0) off[0] = 0;
    }
}
__global__ void k_fill(const int* __restrict__ ei, int E, int* __restrict__ cur,
                       int* __restrict__ lst){
    int e = blockIdx.x*256 + threadIdx.x;
    if (e < E) {
        int pos = atomicAdd(&cur[ei[E+e]], 1);
        lst[pos] = e;
    }
}

// ====================== GAT aggregation with fused edge-softmax ==============
template<bool USE_ATT>
__global__ void k_gather(const ushort* __restrict__ h, const float* __restrict__ scs,
                         const float* __restrict__ scd, const float* __restrict__ att,
                         const int* __restrict__ ei, const int* __restrict__ off,
                         const int* __restrict__ lst, const float* __restrict__ bias,
                         ushort* __restrict__ out, int E, int NN)
{
    int bn = blockIdx.x*4 + (threadIdx.x >> 6);
    int b = bn / NN, n = bn - b*NN;
    int lane = threadIdx.x & 63;
    int c0 = lane*2;
    int hh = lane >> 4;
    float sd = scd[(size_t)bn*4 + hh];
    int o0 = off[n], o1 = off[n+1];
    float ax = 0.f, ay = 0.f, sa = 0.f;
    for (int i = o0; i < o1; ++i) {
        int e = lst[i];
        int s = ei[e];
        float al = scs[(size_t)(b*NN + s)*4 + hh] + sd;
        al = al > 0.f ? al : 0.2f*al;
        float ex = expf(al);
        sa += ex;
        float a = USE_ATT ? ex * att[(size_t)b*E + e] : ex;
        unsigned hv = *(const unsigned*)&h[((size_t)b*NN + s)*128 + c0];
        ax += a * __uint_as_float(hv << 16);
        ay += a * __uint_as_float(hv & 0xffff0000u);
    }
    float rn = (sa > 0.f) ? 1.f/sa : 0.f;   // deg-0 node -> bias only
    ushort2 o2;
    o2.x = f2bf(ax*rn + bias[c0]);
    o2.y = f2bf(ay*rn + bias[c0+1]);
    *(ushort2*)&out[(size_t)bn*128 + c0] = o2;
}

// ============================ weight prep kernels ============================
// ext stage-2 weight: [512][128] fp32 -> [128 cols][512 k] f16
__global__ void k_prepW2(const float* __restrict__ W2, ushort* __restrict__ W2T)
{
    int idx = blockIdx.x*256 + threadIdx.x;   // 512*128
    if (idx >= 512*128) return;
    int k = idx >> 7, c = idx & 127;
    W2T[(size_t)c*512 + k] = f2h(W2[idx]);
}
// generic W[K][N] -> WT[N][K] bf16
__global__ void k_prepT(const float* __restrict__ W, ushort* __restrict__ WT, int K, int N)
{
    int idx = blockIdx.x*256 + threadIdx.x;
    if (idx >= K*N) return;
    int k = idx / N, c = idx - k*N;
    WT[(size_t)c*K + k] = f2bf(W[idx]);
}
// tr_temp_w [56512][128] -> WtT [128][56512] bf16 (tiled)
__global__ void k_prepWtT(const float* __restrict__ W, ushort* __restrict__ WT)
{
    __shared__ ushort tile[128][129];
    int k0 = blockIdx.x * 128;
    int t = threadIdx.x;
    for (int i = t; i < 128*128; i += 256) {
        int k = i >> 7, c = i & 127;
        int kk = k0 + k;
        tile[c][k] = (kk < NDM) ? f2bf(W[(size_t)kk*128 + c]) : (ushort)0;
    }
    __syncthreads();
    for (int i = t; i < 128*128; i += 256) {
        int c = i >> 7, k = i & 127;
        int kk = k0 + k;
        if (kk < NDM) WT[(size_t)c*NDM + kk] = tile[c][k];
    }
}
// inv_temp_w [128][56512] -> WT [56512][128] bf16 (tiled, 64 cols/block)
__global__ void k_prepT_big(const float* __restrict__ W, ushort* __restrict__ WT)
{
    __shared__ float tile[128][65];
    int c0 = blockIdx.x * 64;
    int t = threadIdx.x;
    for (int i = t; i < 128*64; i += 256) {
        int k = i >> 6, ci = i & 63;
        tile[k][ci] = W[(size_t)k*NDM + c0 + ci];
    }
    __syncthreads();
    for (int i = t; i < 64*128; i += 256) {
        int ci = i >> 7, k = i & 127;
        WT[(size_t)(c0 + ci)*128 + k] = f2bf(tile[k][ci]);
    }
}
// bias concat: [b1, zeros]
__global__ void k_bcat(const float* __restrict__ b1, float* __restrict__ dst){
    int i = blockIdx.x*256 + threadIdx.x;
    if (i < 1024) dst[i] = (i < 512) ? b1[i] : 0.f;
}

// ======== MFMA fused extractor stage2 (R11: 4 blocks/CU) =====
// R10 regime note: post-target-sort ext2 runs the gather path at ~4.2 TB/s — BELOW the
// 6.2 TB/s scatter ceiling measured pre-sort (R2). R1's "occupancy doesn't help" null was
// taken in the saturated regime and doesn't transfer. LDS 20KB x4 = 80KB, VGPR 68 both
// permit 4 blocks/CU; more in-flight gathers can fill the 30% slack if latency-limited.
template<bool SWZ>
__launch_bounds__(256, 4)
__global__ void ext2_mfma(const ushort* __restrict__ PQ, const ushort* __restrict__ W2T,
                          const float* __restrict__ b2, const float* __restrict__ w3,
                          const float* __restrict__ b3p, const int* __restrict__ ei,
                          const int* __restrict__ lst,
                          float* __restrict__ att, int E, int NN, int nblk)
{
    __shared__ ushort Bs[2][128*40];
    int bid = blockIdx.x;
    if (SWZ) {
        bid = (blockIdx.x & 7) * (gridDim.x >> 3) + (blockIdx.x >> 3);
        if (bid >= nblk) bid = nblk - 1;
    }
    const int t = threadIdx.x;
    const int wv = t >> 6, l = t & 63;
    const int lr = l & 15, lk = l >> 4;

    const ushort* pr[2]; const ushort* qr[2];
    int row0[2];
    #pragma unroll
    for (int rt = 0; rt < 2; ++rt) {
        row0[rt] = bid*128 + wv*32 + rt*16;
        int r = row0[rt] + lr;
        int b = (int)((unsigned)r / (unsigned)E), i = r - b*E;
        int e = lst[i];                      // CSR position -> edge id (target-sorted)
        pr[rt] = PQ + ((size_t)b*NN + ei[e])*1024 + lk*8;
        qr[rt] = PQ + ((size_t)b*NN + ei[E+e])*1024 + 512 + lk*8;
    }
    // B staging: thread t owns col t>>1, 16-ushort half (t&1)
    const int sc = t >> 1, sh = (t & 1) * 16;
    const ushort* wsrc = W2T + (size_t)sc*512 + sh;
    ushort* wd0 = &Bs[0][sc*40 + sh];
    ushort* wd1 = &Bs[1][sc*40 + sh];

    // prologue: B(0)->LDS[0]; A(0)->regs (first, shallow wait at kc=0 repack); B(1)->regs
    {
        int4 a0 = *(const int4*)(wsrc);
        int4 a1 = *(const int4*)(wsrc + 8);
        *(int4*)wd0 = a0;
        *(int4*)(wd0 + 8) = a1;
    }
    HF8 pu[2], qu[2];
    #pragma unroll
    for (int rt = 0; rt < 2; ++rt) {
        pu[rt].i = *(const int4*)(pr[rt]);
        qu[rt].i = *(const int4*)(qr[rt]);
    }
    int4 bnA = *(const int4*)(wsrc + 32);
    int4 bnB = *(const int4*)(wsrc + 40);
    __syncthreads();

    f32x4 acc[2][8] = {};
    for (int kc = 0; kc < 16; ++kc) {
        const int cb = kc & 1;
        // repack A(kc): relu(P+Q) in packed f16, 2 VALU per dword
        HF8 af[2];
        #pragma unroll
        for (int rt = 0; rt < 2; ++rt)
            #pragma unroll
            for (int j = 0; j < 4; ++j)
                af[rt].w[j] = pkrelu(pkaddh(pu[rt].w[j], qu[rt].w[j]));
        // issue next A-gathers FIRST (deep latency, consumed at kc+1 repack)
        {
            int ka = (kc+1 < 15) ? kc+1 : 15;
            #pragma unroll
            for (int rt = 0; rt < 2; ++rt) {
                pu[rt].i = *(const int4*)(pr[rt] + ka*32);
                qu[rt].i = *(const int4*)(qr[rt] + ka*32);
            }
        }
        // MFMA on LDS[cb] — gather latency hides under this cluster
        __builtin_amdgcn_s_setprio(1);
        #pragma unroll
        for (int ct = 0; ct < 8; ++ct) {
            HF8 bfm;
            bfm.v = *(const f16x8*)&Bs[cb][(ct*16 + lr)*40 + lk*8];
            #pragma unroll
            for (int rt = 0; rt < 2; ++rt)
                acc[rt][ct] = __builtin_amdgcn_mfma_f32_16x16x32_f16(af[rt].v, bfm.v,
                                                                    acc[rt][ct], 0, 0, 0);
        }
        __builtin_amdgcn_s_setprio(0);
        // stage B(kc+1) (regs loaded at kc-1), then reload B(kc+2) LAST
        if (kc < 15) {
            ushort* wd = cb ? wd0 : wd1;
            *(int4*)wd = bnA;
            *(int4*)(wd + 8) = bnB;
        }
        {
            int kb = (kc+2 < 15) ? kc+2 : 15;
            bnA = *(const int4*)(wsrc + kb*32);
            bnB = *(const int4*)(wsrc + kb*32 + 8);
        }
        __syncthreads();
    }
    float b3 = b3p[0];
    #pragma unroll
    for (int rt = 0; rt < 2; ++rt) {
        float part[4] = {0.f,0.f,0.f,0.f};
        #pragma unroll
        for (int ct = 0; ct < 8; ++ct) {
            int c = ct*16 + lr;
            float b2v = b2[c], w3v = w3[c];
            #pragma unroll
            for (int g = 0; g < 4; ++g)
                part[g] += fmaxf(acc[rt][ct][g] + b2v, 0.f) * w3v;
        }
        #pragma unroll
        for (int m = 1; m < 16; m <<= 1)
            #pragma unroll
            for (int g = 0; g < 4; ++g)
                part[g] += __shfl_xor(part[g], m, 64);
        if (lr == 0) {
            #pragma unroll
            for (int g = 0; g < 4; ++g) {
                int rr = row0[rt] + lk*4 + g;
                int b = (int)((unsigned)rr / (unsigned)E), i = rr - b*E;
                int e = lst[i];
                att[(size_t)b*E + e] = 1.f/(1.f + expf(-(part[g] + b3)));
            }
        }
    }
}

// ============================ misc ============================
// fp32 -> bf16 with per-col bias add (fuses the old k_bias_fill: temp_in is memset-0,
// atomics accumulate the GEMM part, bias added here once)
__global__ void k_f2b_bias(const float* __restrict__ src, const float* __restrict__ bias,
                           ushort* __restrict__ dst, int n){
    int i = blockIdx.x*256 + threadIdx.x;
    if (i < n) dst[i] = f2bf(src[i] + bias[i & 127]);
}

// ============================ hid concat (fp32 + bf16 shadow) ============================
__global__ void k_hid(const float* __restrict__ ts_res, const float* __restrict__ ts_temp,
                      const float* __restrict__ node_emb, const float* __restrict__ tid_emb,
                      const float* __restrict__ diw_emb, const float* __restrict__ hist,
                      float* __restrict__ hid, ushort* __restrict__ hidB)
{
    int idx = blockIdx.x*256 + threadIdx.x;
    if (idx >= RBN*320) return;
    int r = idx / 320, c = idx - r*320;
    int b = r / N_, n = r - b*N_;
    float v;
    if (c < 64)        v = ts_res[(size_t)r*64 + c];
    else if (c < 128)  v = ts_temp[(size_t)r*64 + (c-64)];
    else if (c < 192)  v = node_emb[(size_t)n*64 + (c-128)];
    else if (c < 256) {
        int tid = (int)hist[((size_t)(b*L_ + (L_-1))*N_ + n)*3 + 1];
        v = tid_emb[(size_t)tid*64 + (c-192)];
    } else {
        int diw = (int)hist[((size_t)(b*L_ + (L_-1))*N_ + n)*3 + 2];
        v = diw_emb[(size_t)diw*64 + (c-256)];
    }
    hid[idx] = v;
    hidB[idx] = f2bf(v);
}

// =====================================================================================
extern "C" void kernel_launch(void* const* d_in, const int* in_sizes, int n_in,
                              void* d_out, int out_size, void* d_ws, size_t ws_size,
                              hipStream_t stream)
{
    (void)in_sizes; (void)n_in; (void)out_size; (void)ws_size;
    const float* hist      = (const float*)d_in[0];
    const int*   ei_sp     = (const int*)  d_in[1];
    const int*   ei_tp     = (const int*)  d_in[2];
    const float* node_emb  = (const float*)d_in[3];
    const float* tid_emb   = (const float*)d_in[4];
    const float* diw_emb   = (const float*)d_in[5];
    const float* start_w   = (const float*)d_in[6];
    const float* start_b   = (const float*)d_in[7];
    const float* ts_w      = (const float*)d_in[8];
    const float* ts_b      = (const float*)d_in[9];
    const float* tr_spat_w = (const float*)d_in[10];
    const float* tr_spat_b = (const float*)d_in[11];
    const float* inv_spat_w= (const float*)d_in[12];
    const float* inv_spat_b= (const float*)d_in[13];
    const float* tr_temp_w = (const float*)d_in[14];
    const float* tr_temp_b = (const float*)d_in[15];
    const float* inv_temp_w= (const float*)d_in[16];
    const float* inv_temp_b= (const float*)d_in[17];
    const float* gat_sp_w  = (const float*)d_in[18];
    const float* gat_sp_as = (const float*)d_in[19];
    const float* gat_sp_ad = (const float*)d_in[20];
    const float* gat_sp_b  = (const float*)d_in[21];
    const float* ext_sp_w1 = (const float*)d_in[22];
    const float* ext_sp_b1 = (const float*)d_in[23];
    const float* ext_sp_w2 = (const float*)d_in[24];
    const float* ext_sp_b2 = (const float*)d_in[25];
    const float* ext_sp_w3 = (const float*)d_in[26];
    const float* ext_sp_b3 = (const float*)d_in[27];
    const float* gat_tp_w  = (const float*)d_in[28];
    const float* gat_tp_as = (const float*)d_in[29];
    const float* gat_tp_ad = (const float*)d_in[30];
    const float* gat_tp_b  = (const float*)d_in[31];
    const float* ext_tp_w1 = (const float*)d_in[32];
    const float* ext_tp_b1 = (const float*)d_in[33];
    const float* ext_tp_w2 = (const float*)d_in[34];
    const float* ext_tp_b2 = (const float*)d_in[35];
    const float* ext_tp_w3 = (const float*)d_in[36];
    const float* ext_tp_b3 = (const float*)d_in[37];
    const float* enc_w1    = (const float*)d_in[38];
    const float* enc_b1    = (const float*)d_in[39];
    const float* enc_w2    = (const float*)d_in[40];
    const float* enc_b2    = (const float*)d_in[41];
    const float* reg_w     = (const float*)d_in[42];
    const float* reg_b     = (const float*)d_in[43];
    float* out = (float*)d_out;

    // ---------------- workspace layout (byte-granular, 256B aligned) ----------------
    size_t o = 0;
    char* wsb = (char*)d_ws;
    auto allocB = [&](size_t bytes) -> void* {
        void* p = wsb + o;
        o += (bytes + 255) & ~(size_t)255;
        return p;
    };
    // big reusable arenas
    void* bufA = allocB((size_t)RBN*768*2);   // hid fp32[RBN][320]
    void* bufB = allocB((size_t)RBN*768*2);   // PQ_sp[RBN][1024]f16 (spills into bufC)
    void* bufC = allocB((size_t)RBN*512*2);   // (PQ_sp tail) -> hidB[RBN][320]bf16
    void* bufD = allocB((size_t)RBN*320*2);   // R1b (encoder temp bf16)
    float*  ts_res  = (float*)allocB((size_t)RBN*64*4);
    ushort* spaB    = (ushort*)allocB((size_t)RBN*128*2);  // spa_in -> spa_out
    ushort* hB      = (ushort*)allocB((size_t)RBN*128*2);  // h_sp -> h_tp
    float*  sc_s    = (float*)allocB((size_t)RBN*4*4);
    float*  sc_d    = (float*)allocB((size_t)RBN*4*4);
    float*  att     = (float*)allocB((size_t)B_*E_SP*4);
    ushort* embB    = (ushort*)allocB((size_t)RBN*128*2);
    int*    csr     = (int*)allocB(17024*4);
    float*  temp_in = (float*)allocB((size_t)RBL*128*4);
    ushort* tempB   = (ushort*)allocB((size_t)RBL*128*2);
    ushort* toutB   = (ushort*)allocB((size_t)RBL*128*2);
    ushort* PQ_t    = (ushort*)allocB((size_t)RBL*1024*2);
    float*  ts_temp = (float*)allocB((size_t)RBN*64*4);
    // weight preps
    ushort* W2T_sp  = (ushort*)allocB(512*128*2);
    ushort* W2T_tp  = (ushort*)allocB(512*128*2);
    ushort* WtT     = (ushort*)allocB((size_t)128*NDM*2);   // tr_temp_w^T
    ushort* itWT    = (ushort*)allocB((size_t)NDM*128*2);   // inv_temp_w^T
    ushort* ispWT   = (ushort*)allocB(768*128*2);           // inv_spat_w^T
    ushort* gspWT   = (ushort*)allocB(128*128*2);
    ushort* gtpWT   = (ushort*)allocB(128*128*2);
    ushort* w1catT_sp = (ushort*)allocB((size_t)1024*128*2);
    ushort* w1catT_tp = (ushort*)allocB((size_t)1024*128*2);
    float*  b1cat_sp  = (float*)allocB(1024*4);
    float*  b1cat_tp  = (float*)allocB(1024*4);
    ushort* w1T_enc = (ushort*)allocB((size_t)3*320*320*2);
    ushort* w2T_enc = (ushort*)allocB((size_t)3*320*320*2);
    ushort* tswT_hi = (ushort*)allocB(64*768*2);
    ushort* reg_wT  = (ushort*)allocB(16*320*2);
    float*  A1      = (float*)allocB(36*64*4);
    float*  A2      = (float*)allocB(36*128*4);
    float*  cb1     = (float*)allocB(64*4);
    float*  cb2     = (float*)allocB(128*4);

    float*  hid   = (float*)bufA;     // [RBN][320] fp32
    ushort* PQ_sp = (ushort*)bufB;    // [RBN][1024] f16 (57.9 MB, spans bufB+bufC)
    ushort* hidB  = (ushort*)bufC;
    ushort* R1b   = (ushort*)bufD;

    int* counts_sp = csr;
    int* off_sp    = csr + 883;
    int* cur_sp    = csr + 1767;
    int* list_sp   = csr + 2650;
    int* counts_tp = csr + 16778;
    int* off_tp    = csr + 16790;
    int* cur_tp    = csr + 16803;
    int* list_tp   = csr + 16815;

    // ---------------- CSR builds + weight prep ----------------
    hipMemsetAsync(counts_sp, 0, 883*4, stream);
    k_count<<<cdiv_h(E_SP,256),256,0,stream>>>(ei_sp, E_SP, counts_sp);
    k_scan<<<1,1024,0,stream>>>(counts_sp, off_sp, cur_sp, 883);
    k_fill<<<cdiv_h(E_SP,256),256,0,stream>>>(ei_sp, E_SP, cur_sp, list_sp);
    hipMemsetAsync(counts_tp, 0, 12*4, stream);
    k_count<<<1,256,0,stream>>>(ei_tp, E_TP, counts_tp);
    k_scan<<<1,1024,0,stream>>>(counts_tp, off_tp, cur_tp, 12);
    k_fill<<<1,256,0,stream>>>(ei_tp, E_TP, cur_tp, list_tp);
    k_mkA<<<cdiv_h(36*64+36*128+192,256),256,0,stream>>>(start_w, start_b, ts_w, ts_b,
                                                         tr_spat_w, tr_spat_b,
                                                         A1, A2, cb1, cb2);
    k_prepW2<<<cdiv_h(512*128,256),256,0,stream>>>(ext_sp_w2, W2T_sp);
    k_prepW2<<<cdiv_h(512*128,256),256,0,stream>>>(ext_tp_w2, W2T_tp);
    k_prepWtT<<<cdiv_h(NDM,128),256,0,stream>>>(tr_temp_w, WtT);
    k_prepT_big<<<NDM/64,256,0,stream>>>(inv_temp_w, itWT);
    k_prepT<<<cdiv_h(128*768,256),256,0,stream>>>(inv_spat_w, ispWT, 128, 768);
    k_prepT<<<cdiv_h(128*128,256),256,0,stream>>>(gat_sp_w, gspWT, 128, 128);
    k_prepT<<<cdiv_h(128*128,256),256,0,stream>>>(gat_tp_w, gtpWT, 128, 128);
    k_prepT<<<cdiv_h(128*512,256),256,0,stream>>>(ext_sp_w1,           w1catT_sp,           128, 512);
    k_prepT<<<cdiv_h(128*512,256),256,0,stream>>>(ext_sp_w1 + 128*512, w1catT_sp + 512*128, 128, 512);
    k_prepT<<<cdiv_h(128*512,256),256,0,stream>>>(ext_tp_w1,           w1catT_tp,           128, 512);
    k_prepT<<<cdiv_h(128*512,256),256,0,stream>>>(ext_tp_w1 + 128*512, w1catT_tp + 512*128, 128, 512);
    k_bcat<<<4,256,0,stream>>>(ext_sp_b1, b1cat_sp);
    k_bcat<<<4,256,0,stream>>>(ext_tp_b1, b1cat_tp);
    for (int i = 0; i < 3; ++i) {
        k_prepT<<<cdiv_h(320*320,256),256,0,stream>>>(enc_w1 + (size_t)i*320*320, w1T_enc + (size_t)i*320*320, 320, 320);
        k_prepT<<<cdiv_h(320*320,256),256,0,stream>>>(enc_w2 + (size_t)i*320*320, w2T_enc + (size_t)i*320*320, 320, 320);
    }
    k_prepT<<<cdiv_h(768*64,256),256,0,stream>>>(ts_w, tswT_hi, 768, 64);
    hipMemsetAsync(reg_wT, 0, 16*320*2, stream);
    k_prepT<<<cdiv_h(320*12,256),256,0,stream>>>(reg_w, reg_wT, 320, 12);

    // ---------------- fused front chain: ts_res (fp32) + spa_in (bf16) from hist ----------
    k_front<<<cdiv_h(RBN*192,256),256,0,stream>>>(hist, A1, A2, cb1, cb2, ts_res, spaB);

    // ---------------- spatial GAT ----------------
    mgemm_rt<2,4,0,false,false><<<dim3(2,221),256,0,stream>>>(spaB, gspWT, nullptr, nullptr,
                                                              hB, RBN, 128, 128);
    k_sc<<<cdiv_h(RBN,16),256,0,stream>>>(hB, gat_sp_as, gat_sp_ad, sc_s, sc_d, RBN);
    k_gather<false><<<RBN/4,256,0,stream>>>(hB, sc_s, sc_d, nullptr, ei_sp, off_sp, list_sp,
                                            gat_sp_b, embB, E_SP, N_);
    // extractor: PQ = emb@[W1a|W1b] + [b1|0] (f16); att = sigmoid(MLP) via f16 MFMA
    // R11: CT 8->16, grid.x 8->4 (halves A re-read: 58->29 MB HBM)
    mgemm_rt<2,16,4,false,false><<<dim3(4,221),256,0,stream>>>(embB, w1catT_sp, b1cat_sp, nullptr,
                                                               PQ_sp, RBN, 1024, 128);
    ext2_mfma<true><<<3536,256,0,stream>>>(PQ_sp, W2T_sp, ext_sp_b2, ext_sp_w3, ext_sp_b3,
                                           ei_sp, list_sp, att, E_SP, N_, (B_*E_SP)/128);
    k_gather<true><<<RBN/4,256,0,stream>>>(hB, sc_s, sc_d, att, ei_sp, off_sp, list_sp,
                                           gat_sp_b, spaB, E_SP, N_);

    // ---------------- fused spatial back-projection + temporal input ----------------
    hipMemsetAsync(temp_in, 0, (size_t)RBL*128*4, stream);
    k_tempIn<<<dim3(cdiv_h(N_,TNC),2),256,0,stream>>>(spaB, ispWT, inv_spat_b, WtT, temp_in);
    k_f2b_bias<<<cdiv_h(RBL*128,256),256,0,stream>>>(temp_in, tr_temp_b, tempB, RBL*128);

    // ---------------- temporal GAT ----------------
    mgemm_rt<2,4,0,false,false><<<dim3(2,3),256,0,stream>>>(tempB, gtpWT, nullptr, nullptr,
                                                            hB, RBL, 128, 128);
    k_sc<<<cdiv_h(RBL,16),256,0,stream>>>(hB, gat_tp_as, gat_tp_ad, sc_s, sc_d, RBL);
    k_gather<false><<<RBL/4,256,0,stream>>>(hB, sc_s, sc_d, nullptr, ei_tp, off_tp, list_tp,
                                            gat_tp_b, embB, E_TP, NT_);
    mgemm_rt<2,16,4,false,false><<<dim3(4,3),256,0,stream>>>(embB, w1catT_tp, b1cat_tp, nullptr,
                                                             PQ_t, RBL, 1024, 128);
    ext2_mfma<false><<<(B_*E_TP)/128,256,0,stream>>>(PQ_t, W2T_tp, ext_tp_b2, ext_tp_w3,
                                                     ext_tp_b3, ei_tp, list_tp, att, E_TP, NT_,
                                                     (B_*E_TP)/128);
    k_gather<true><<<RBL/4,256,0,stream>>>(hB, sc_s, sc_d, att, ei_tp, off_tp, list_tp,
                                           gat_tp_b, toutB, E_TP, NT_);

    // ---------------- fused temporal back-projection + ts_temp ----------------
    k_tsTemp<<<N_,256,0,stream>>>(toutB, itWT, inv_temp_b, tswT_hi, ts_b, ts_temp);

    // ---------------- concat + residual MLP encoder (R8 proven form) + head ---------
    k_hid<<<cdiv_h(RBN*320,256),256,0,stream>>>(ts_res, ts_temp, node_emb, tid_emb, diw_emb, hist,
                                                hid, hidB);
    for (int i = 0; i < 3; ++i) {
        mgemm_rt<2,10,0,true,false><<<dim3(2,221),256,0,stream>>>(hidB, w1T_enc + (size_t)i*320*320,
                                                                  enc_b1 + i*320, nullptr, R1b, RBN, 320, 320);
        mgemm_rt<2,10,0,false,true><<<dim3(2,221),256,0,stream>>>(R1b, w2T_enc + (size_t)i*320*320,
                                                                  enc_b2 + i*320, hid, hidB, RBN, 320, 320);
    }
    mgemm<1,0,2,false,false><<<dim3(1,442),256,0,stream>>>(hidB, reg_wT, reg_b, nullptr,
                                                           out, RBN, 16, 320);
}

// Round 12
// 1188.935 us; speedup vs baseline: 1.0636x; 1.0636x over previous
//
#include <hip/hip_runtime.h>
#include <hip/hip_bf16.h>
#include <cstdint>
#include <cstddef>

#define B_   32
#define L_   12
#define N_   883
#define DM_  64
#define E_SP 14128
#define E_TP 144
#define NT_  12
#define RBN  28256      // B*N
#define RBL  384        // B*L
#define LDM  768        // L*DM
#define NDM  56512      // N*DM

static inline int cdiv_h(int a, int b){ return (a+b-1)/b; }

// bf16 round-to-nearest-even from float
__device__ __forceinline__ ushort f2bf(float f){
    unsigned u = __float_as_uint(f);
    unsigned lsb = (u >> 16) & 1u;
    u += 0x7fffu + lsb;
    return (ushort)(u >> 16);
}
__device__ __forceinline__ float bf2f(ushort h){
    return __uint_as_float(((unsigned)h) << 16);
}
// fp16 RNE from float (v_cvt_f16_f32)
__device__ __forceinline__ ushort f2h(float f){
    _Float16 h = (_Float16)f;
    ushort r; __builtin_memcpy(&r, &h, 2);
    return r;
}

typedef __bf16 bf16x8 __attribute__((ext_vector_type(8)));
typedef _Float16 f16x8 __attribute__((ext_vector_type(8)));
typedef _Float16 f16x2 __attribute__((ext_vector_type(2)));
typedef float  f32x4  __attribute__((ext_vector_type(4)));
typedef short  s16x2  __attribute__((ext_vector_type(2)));
union BF8 { bf16x8 v; ushort u[8]; unsigned w[4]; int4 i; };
union HF8 { f16x8 v; ushort u[8]; unsigned w[4]; int4 i; };

// packed relu on 2 half-precision values (sign-magnitude => signed-i16 max-with-0 is exact relu)
__device__ __forceinline__ unsigned pkrelu(unsigned x){
    s16x2 v;
    __builtin_memcpy(&v, &x, 4);
    s16x2 z = 0;
    v = __builtin_elementwise_max(v, z);
    unsigned r;
    __builtin_memcpy(&r, &v, 4);
    return r;
}
// packed f16 add (v_pk_add_f16): 1 VALU for 2 elements
__device__ __forceinline__ unsigned pkaddh(unsigned x, unsigned y){
    f16x2 a, b;
    __builtin_memcpy(&a, &x, 4);
    __builtin_memcpy(&b, &y, 4);
    a = a + b;
    unsigned r;
    __builtin_memcpy(&r, &a, 4);
    return r;
}

// ========== front-chain collapse (R5/R6) ==========
__global__ void k_mkA(const float* __restrict__ sw, const float* __restrict__ sb,
                      const float* __restrict__ tsw, const float* __restrict__ tsb,
                      const float* __restrict__ trsp, const float* __restrict__ trspb,
                      float* __restrict__ A1, float* __restrict__ A2,
                      float* __restrict__ cb1, float* __restrict__ cb2)
{
    int idx = blockIdx.x*256 + threadIdx.x;
    if (idx < 36*64) {
        int k = idx >> 6, h = idx & 63;
        int l = k/3, c = k - l*3;
        float s = 0.f;
        #pragma unroll 8
        for (int d = 0; d < 64; ++d) s += sw[c*64+d]*tsw[(size_t)(l*64+d)*64 + h];
        A1[idx] = s;
    } else if (idx < 36*64 + 36*128) {
        int i = idx - 36*64;
        int k = i >> 7, p = i & 127;
        int l = k/3, c = k - l*3;
        float s = 0.f;
        #pragma unroll 8
        for (int d = 0; d < 64; ++d) s += sw[c*64+d]*trsp[(size_t)(l*64+d)*128 + p];
        A2[i] = s;
    } else if (idx < 36*64 + 36*128 + 64) {
        int h = idx - (36*64 + 36*128);
        float s = tsb[h];
        #pragma unroll 8
        for (int k = 0; k < 768; ++k) s += sb[k & 63]*tsw[(size_t)k*64 + h];
        cb1[h] = s;
    } else if (idx < 36*64 + 36*128 + 64 + 128) {
        int p = idx - (36*64 + 36*128 + 64);
        float s = trspb[p];
        #pragma unroll 8
        for (int k = 0; k < 768; ++k) s += sb[k & 63]*trsp[(size_t)k*128 + p];
        cb2[p] = s;
    }
}
// one thread per (bn, h), h in [0,192): h<64 -> ts_res fp32, else spa_in bf16.
__global__ void k_front(const float* __restrict__ hist, const float* __restrict__ A1,
                        const float* __restrict__ A2, const float* __restrict__ cb1,
                        const float* __restrict__ cb2, float* __restrict__ ts_res,
                        ushort* __restrict__ spa_in)
{
    int idx = blockIdx.x*256 + threadIdx.x;
    if (idx >= RBN*192) return;
    int bn = idx / 192, h = idx - bn*192;
    int b = bn / N_, n = bn - b*N_;
    const float* hp = hist + ((size_t)(b*L_)*N_ + n)*3;   // + l*2649 per lag
    bool isTs = (h < 64);
    int hh = isTs ? h : (h - 64);
    int stride = isTs ? 64 : 128;
    const float* A = isTs ? (A1 + hh) : (A2 + hh);
    float acc = isTs ? cb1[hh] : cb2[hh];
    #pragma unroll
    for (int l = 0; l < 12; ++l) {
        float x0 = hp[l*2649 + 0];
        float x1 = hp[l*2649 + 1];
        float x2 = hp[l*2649 + 2];
        acc += x0*A[(l*3+0)*stride] + x1*A[(l*3+1)*stride] + x2*A[(l*3+2)*stride];
    }
    if (isTs) ts_res[(size_t)bn*64 + hh] = acc;
    else      spa_in[(size_t)bn*128 + hh] = f2bf(acc);
}

// ============== generalized MFMA GEMM (direct-from-global), 1 row-tile/wave ==============
template<int CT, int AMODE, int EPI, bool RELU, bool RES>
__launch_bounds__(256)
__global__ void mgemm(const ushort* __restrict__ A, const ushort* __restrict__ WT,
                      const float* __restrict__ bias, float* __restrict__ resF,
                      void* __restrict__ outP, int M, int N, int K)
{
    const int t = threadIdx.x, wv = t >> 6, l = t & 63;
    const int lr = l & 15, lk = l >> 4;
    const int row0 = blockIdx.y*64 + wv*16;
    const int col0 = blockIdx.x * (CT*16);
    int arr = row0 + lr; if (arr >= M) arr = M-1;
    int ab = 0, an = 0;
    if (AMODE == 1) { ab = arr / N_; an = arr - ab*N_; }
    const ushort* ap = A + (size_t)arr*K + lk*8;
    f32x4 acc[CT] = {};
    for (int k0 = 0; k0 < K; k0 += 32) {
        BF8 af;
        if (AMODE == 0) af.i = *(const int4*)(ap + k0);
        else {
            int k = k0 + lk*8; int ll = k >> 6, d = k & 63;
            af.i = *(const int4*)(A + ((size_t)(ab*L_ + ll))*NDM + (size_t)an*64 + d);
        }
        #pragma unroll
        for (int ct = 0; ct < CT; ++ct) {
            BF8 bf; bf.i = *(const int4*)&WT[(size_t)(col0 + ct*16 + lr)*K + k0 + lk*8];
            acc[ct] = __builtin_amdgcn_mfma_f32_16x16x32_bf16(af.v, bf.v, acc[ct], 0, 0, 0);
        }
    }
    #pragma unroll
    for (int ct = 0; ct < CT; ++ct) {
        int c = col0 + ct*16 + lr;
        float bv = 0.f;
        if (EPI == 2) { if (bias && c < 12) bv = bias[c]; }
        else if (bias) bv = bias[c];
        #pragma unroll
        for (int g = 0; g < 4; ++g) {
            int r = row0 + lk*4 + g;
            if (r >= M) continue;
            float v = acc[ct][g] + bv;
            if (RELU) v = fmaxf(v, 0.f);
            if (RES) {
                v += resF[(size_t)r*N + c];
                resF[(size_t)r*N + c] = v;
            }
            if (EPI == 0) {
                ((ushort*)outP)[(size_t)r*N + c] = f2bf(v);
            } else if (EPI == 1) {
                ((float*)outP)[(size_t)r*N + c] = v;
            } else if (EPI == 2) {
                if (c < 12) {
                    int b = r / N_, n = r - (r/N_)*N_;
                    ((float*)outP)[((size_t)(b*L_ + c))*N_ + n] = v;
                }
            } else {
                int b = r / N_, n = r - (r/N_)*N_;
                ((ushort*)outP)[((size_t)(b*L_ + (c>>6)))*NDM + (size_t)n*64 + (c&63)] = f2bf(v);
            }
        }
    }
}

// ============== MFMA GEMM with RT row-tiles/wave (B-load amortization) ==============
// EPI 4: f16 out[r*N+c] (for the extractor PQ buffers consumed by ext2_mfma's packed-f16 path).
template<int RT, int CT, int EPI, bool RELU, bool RES>
__launch_bounds__(256)
__global__ void mgemm_rt(const ushort* __restrict__ A, const ushort* __restrict__ WT,
                         const float* __restrict__ bias, float* __restrict__ resF,
                         void* __restrict__ outP, int M, int N, int K)
{
    const int t = threadIdx.x, wv = t >> 6, l = t & 63;
    const int lr = l & 15, lk = l >> 4;
    const int rowbase = blockIdx.y*(4*RT*16) + wv*(RT*16);
    const int col0 = blockIdx.x * (CT*16);
    const ushort* ap[RT];
    #pragma unroll
    for (int rt = 0; rt < RT; ++rt) {
        int arr = rowbase + rt*16 + lr; if (arr >= M) arr = M-1;
        ap[rt] = A + (size_t)arr*K + lk*8;
    }
    f32x4 acc[RT][CT] = {};
    for (int k0 = 0; k0 < K; k0 += 32) {
        BF8 af[RT];
        #pragma unroll
        for (int rt = 0; rt < RT; ++rt) af[rt].i = *(const int4*)(ap[rt] + k0);
        #pragma unroll
        for (int ct = 0; ct < CT; ++ct) {
            BF8 bf; bf.i = *(const int4*)&WT[(size_t)(col0 + ct*16 + lr)*K + k0 + lk*8];
            #pragma unroll
            for (int rt = 0; rt < RT; ++rt)
                acc[rt][ct] = __builtin_amdgcn_mfma_f32_16x16x32_bf16(af[rt].v, bf.v,
                                                                     acc[rt][ct], 0, 0, 0);
        }
    }
    #pragma unroll
    for (int rt = 0; rt < RT; ++rt)
        #pragma unroll
        for (int ct = 0; ct < CT; ++ct) {
            int c = col0 + ct*16 + lr;
            float bv = bias ? bias[c] : 0.f;
            #pragma unroll
            for (int g = 0; g < 4; ++g) {
                int r = rowbase + rt*16 + lk*4 + g;
                if (r >= M) continue;
                float v = acc[rt][ct][g] + bv;
                if (RELU) v = fmaxf(v, 0.f);
                if (RES) {
                    v += resF[(size_t)r*N + c];
                    resF[(size_t)r*N + c] = v;
                }
                if (EPI == 0) {
                    ((ushort*)outP)[(size_t)r*N + c] = f2bf(v);
                } else if (EPI == 1) {
                    ((float*)outP)[(size_t)r*N + c] = v;
                } else if (EPI == 4) {
                    ((ushort*)outP)[(size_t)r*N + c] = f2h(v);
                } else {  // EPI 3: bf16 AT scatter
                    int b = r / N_, n = r - (r/N_)*N_;
                    ((ushort*)outP)[((size_t)(b*L_ + (c>>6)))*NDM + (size_t)n*64 + (c&63)] = f2bf(v);
                }
            }
        }
}

// ======== fused spatial back-projection + temporal input (R8, proven) ========
#define TNC 8
__launch_bounds__(256)
__global__ void k_tempIn(const ushort* __restrict__ spaB, const ushort* __restrict__ ispWT,
                         const float* __restrict__ isb, const ushort* __restrict__ WtT,
                         float* __restrict__ out)
{
    __shared__ ushort T1[16*768];   // [b_local][(l*64+d) swizzled], bf16, 24KB
    const int t = threadIdx.x, wv = t >> 6, l = t & 63;
    const int lr = l & 15, lk = l >> 4;
    const int bh = blockIdx.y;                 // b-half: b = bh*16 + b_local
    const int n0 = blockIdx.x * TNC;
    const int nEnd = (n0 + TNC < N_) ? n0 + TNC : N_;

    f32x4 acc2[3][8] = {};
    for (int n = n0; n < nEnd; ++n) {
        // ---- stage 1 (reads global only; safe before barrier)
        f32x4 acc1[12] = {};
        for (int k0 = 0; k0 < 128; k0 += 32) {
            BF8 af; af.i = *(const int4*)&spaB[((size_t)(bh*16 + lr)*N_ + n)*128 + k0 + lk*8];
            #pragma unroll
            for (int ct = 0; ct < 12; ++ct) {
                BF8 bf; bf.i = *(const int4*)&ispWT[(size_t)(wv*192 + ct*16 + lr)*128 + k0 + lk*8];
                acc1[ct] = __builtin_amdgcn_mfma_f32_16x16x32_bf16(af.v, bf.v, acc1[ct], 0, 0, 0);
            }
        }
        __syncthreads();   // prev node's stage-2 reads done before overwriting T1
        #pragma unroll
        for (int ct = 0; ct < 12; ++ct) {
            int c = wv*192 + ct*16 + lr;       // (l*64+d)
            float bv = isb[c];
            int ll = c >> 6, d = c & 63;
            #pragma unroll
            for (int g = 0; g < 4; ++g) {
                int b = lk*4 + g;              // local b 0..15
                int r = b*12 + ll;
                T1[b*768 + ll*64 + (d ^ ((r & 7) << 3))] = f2bf(acc1[ct][g] + bv);
            }
        }
        __syncthreads();
        // ---- stage 2: acc2 += T1[192][64] @ Wt_n
        #pragma unroll
        for (int kc = 0; kc < 2; ++kc) {
            BF8 bfr[8];
            #pragma unroll
            for (int ct = 0; ct < 8; ++ct)
                bfr[ct].i = *(const int4*)&WtT[(size_t)(ct*16 + lr)*NDM + (size_t)n*64 + kc*32 + lk*8];
            #pragma unroll
            for (int rt = 0; rt < 3; ++rt) {
                int r = wv*48 + rt*16 + lr;    // local row (b_local*12 + l), 0..191
                int b = r / 12, ll = r - b*12;
                int k = kc*32 + lk*8;
                BF8 af;
                af.v = *(const bf16x8*)&T1[b*768 + ll*64 + (k ^ ((r & 7) << 3))];
                #pragma unroll
                for (int ct = 0; ct < 8; ++ct)
                    acc2[rt][ct] = __builtin_amdgcn_mfma_f32_16x16x32_bf16(af.v, bfr[ct].v,
                                                                          acc2[rt][ct], 0, 0, 0);
            }
        }
    }
    #pragma unroll
    for (int rt = 0; rt < 3; ++rt)
        #pragma unroll
        for (int ct = 0; ct < 8; ++ct) {
            int p = ct*16 + lr;
            #pragma unroll
            for (int g = 0; g < 4; ++g) {
                int r = bh*192 + wv*48 + rt*16 + lk*4 + g;
                atomicAdd(&out[(size_t)r*128 + p], acc2[rt][ct][g]);
            }
        }
}

// ======== fused temporal back-projection + ts_temp (R7, proven) ========
__launch_bounds__(256)
__global__ void k_tsTemp(const ushort* __restrict__ toutB, const ushort* __restrict__ itWT,
                         const float* __restrict__ itb, const ushort* __restrict__ tswT,
                         const float* __restrict__ tsb, float* __restrict__ ts_temp)
{
    __shared__ ushort sb[384*72];   // row (b*12+l), 64 d + 8 pad, bf16
    const int n = blockIdx.x;
    const int t = threadIdx.x, wv = t >> 6, l = t & 63;
    const int lr = l & 15, lk = l >> 4;
    // ---- stage 1: wave wv -> rows wv*96..+95 (6 RT), cols 0..63 (4 CT), K=128 (4 kc)
    {
        f32x4 acc1[6][4] = {};
        for (int k0 = 0; k0 < 128; k0 += 32) {
            BF8 bfr[4];
            #pragma unroll
            for (int ct = 0; ct < 4; ++ct)
                bfr[ct].i = *(const int4*)&itWT[(size_t)(n*64 + ct*16 + lr)*128 + k0 + lk*8];
            #pragma unroll
            for (int rt = 0; rt < 6; ++rt) {
                BF8 af; af.i = *(const int4*)&toutB[(size_t)(wv*96 + rt*16 + lr)*128 + k0 + lk*8];
                #pragma unroll
                for (int ct = 0; ct < 4; ++ct)
                    acc1[rt][ct] = __builtin_amdgcn_mfma_f32_16x16x32_bf16(af.v, bfr[ct].v,
                                                                          acc1[rt][ct], 0, 0, 0);
            }
        }
        #pragma unroll
        for (int rt = 0; rt < 6; ++rt)
            #pragma unroll
            for (int ct = 0; ct < 4; ++ct) {
                int d = ct*16 + lr;
                float bv = itb[n*64 + d];
                #pragma unroll
                for (int g = 0; g < 4; ++g) {
                    int r = wv*96 + rt*16 + lk*4 + g;   // (b*12+l)
                    int bb = r / 12;
                    sb[r*72 + (d ^ ((bb & 7) << 3))] = f2bf(acc1[rt][ct][g] + bv);
                }
            }
    }
    __syncthreads();
    // ---- stage 2: wave wv -> cols wv*16..+15 (1 CT), rows 0..31 (2 RT), K=768 (24 kc)
    f32x4 acc2[2] = {};
    #pragma unroll 2
    for (int j = 0; j < 24; ++j) {
        BF8 bfm; bfm.i = *(const int4*)&tswT[(size_t)(wv*16 + lr)*768 + j*32 + lk*8];
        int lidx = j >> 1;
        int koff = (j & 1)*32 + lk*8;
        #pragma unroll
        for (int rt = 0; rt < 2; ++rt) {
            int bb = rt*16 + lr;
            BF8 af;
            af.v = *(const bf16x8*)&sb[(bb*12 + lidx)*72 + (koff ^ ((bb & 7) << 3))];
            acc2[rt] = __builtin_amdgcn_mfma_f32_16x16x32_bf16(af.v, bfm.v, acc2[rt], 0, 0, 0);
        }
    }
    {
        int h = wv*16 + lr;
        float bv = tsb[h];
        #pragma unroll
        for (int rt = 0; rt < 2; ++rt)
            #pragma unroll
            for (int g = 0; g < 4; ++g) {
                int bb = rt*16 + lk*4 + g;
                ts_temp[((size_t)bb*N_ + n)*64 + h] = acc2[rt][g] + bv;
            }
    }
}

// ============================ attention scores (R9: vectorized, 16 lanes/row) ============
__global__ void k_sc(const ushort* __restrict__ h, const float* __restrict__ as_,
                     const float* __restrict__ ad_, float* __restrict__ scs,
                     float* __restrict__ scd, int R)
{
    int wid = blockIdx.x*4 + (threadIdx.x >> 6);
    int l = threadIdx.x & 63;
    int sub = l >> 4;          // 4 rows per wave
    int j = l & 15;            // 16 lanes per row
    int r = wid*4 + sub;
    if (r >= R) r = R - 1;     // duplicate work on tail, benign
    BF8 hv; hv.i = *(const int4*)&h[(size_t)r*128 + j*8];
    int hh = j >> 2;
    const float* pa = as_ + hh*32 + (j & 3)*8;
    const float* pd = ad_ + hh*32 + (j & 3)*8;
    float ss = 0.f, sd = 0.f;
    #pragma unroll
    for (int k = 0; k < 8; ++k) {
        float x = bf2f(hv.u[k]);
        ss += x*pa[k];
        sd += x*pd[k];
    }
    ss += __shfl_xor(ss, 1, 64); ss += __shfl_xor(ss, 2, 64);
    sd += __shfl_xor(sd, 1, 64); sd += __shfl_xor(sd, 2, 64);
    if ((j & 3) == 0) {
        scs[(size_t)r*4 + hh] = ss;
        scd[(size_t)r*4 + hh] = sd;
    }
}

// ============================ CSR build (target-indexed) ============================
__global__ void k_count(const int* __restrict__ ei, int E, int* __restrict__ counts){
    int e = blockIdx.x*256 + threadIdx.x;
    if (e < E) atomicAdd(&counts[ei[E + e]], 1);
}
__global__ void k_scan(const int* __restrict__ counts, int* __restrict__ off,
                       int* __restrict__ cur, int n)
{
    __shared__ int s[1024];
    int t = threadIdx.x;
    int v0 = (t < n) ? counts[t] : 0;
    s[t] = v0;
    __syncthreads();
    for (int o = 1; o < 1024; o <<= 1) {
        int v = (t >= o) ? s[t-o] : 0;
        __syncthreads();
        s[t] += v;
        __syncthreads();
    }
    if (t < n) {
        off[t+1] = s[t];
        cur[t] = s[t] - v0;
        if (t == 0) off[0] = 0;
    }
}
__global__ void k_fill(const int* __restrict__ ei, int E, int* __restrict__ cur,
                       int* __restrict__ lst){
    int e = blockIdx.x*256 + threadIdx.x;
    if (e < E) {
        int pos = atomicAdd(&cur[ei[E+e]], 1);
        lst[pos] = e;
    }
}

// ====================== GAT aggregation with fused edge-softmax ==============
template<bool USE_ATT>
__global__ void k_gather(const ushort* __restrict__ h, const float* __restrict__ scs,
                         const float* __restrict__ scd, const float* __restrict__ att,
                         const int* __restrict__ ei, const int* __restrict__ off,
                         const int* __restrict__ lst, const float* __restrict__ bias,
                         ushort* __restrict__ out, int E, int NN)
{
    int bn = blockIdx.x*4 + (threadIdx.x >> 6);
    int b = bn / NN, n = bn - b*NN;
    int lane = threadIdx.x & 63;
    int c0 = lane*2;
    int hh = lane >> 4;
    float sd = scd[(size_t)bn*4 + hh];
    int o0 = off[n], o1 = off[n+1];
    float ax = 0.f, ay = 0.f, sa = 0.f;
    for (int i = o0; i < o1; ++i) {
        int e = lst[i];
        int s = ei[e];
        float al = scs[(size_t)(b*NN + s)*4 + hh] + sd;
        al = al > 0.f ? al : 0.2f*al;
        float ex = expf(al);
        sa += ex;
        float a = USE_ATT ? ex * att[(size_t)b*E + e] : ex;
        unsigned hv = *(const unsigned*)&h[((size_t)b*NN + s)*128 + c0];
        ax += a * __uint_as_float(hv << 16);
        ay += a * __uint_as_float(hv & 0xffff0000u);
    }
    float rn = (sa > 0.f) ? 1.f/sa : 0.f;   // deg-0 node -> bias only
    ushort2 o2;
    o2.x = f2bf(ax*rn + bias[c0]);
    o2.y = f2bf(ay*rn + bias[c0+1]);
    *(ushort2*)&out[(size_t)bn*128 + c0] = o2;
}

// ============================ weight prep kernels ============================
// ext stage-2 weight: [512][128] fp32 -> [128 cols][512 k] f16
__global__ void k_prepW2(const float* __restrict__ W2, ushort* __restrict__ W2T)
{
    int idx = blockIdx.x*256 + threadIdx.x;   // 512*128
    if (idx >= 512*128) return;
    int k = idx >> 7, c = idx & 127;
    W2T[(size_t)c*512 + k] = f2h(W2[idx]);
}
// generic W[K][N] -> WT[N][K] bf16
__global__ void k_prepT(const float* __restrict__ W, ushort* __restrict__ WT, int K, int N)
{
    int idx = blockIdx.x*256 + threadIdx.x;
    if (idx >= K*N) return;
    int k = idx / N, c = idx - k*N;
    WT[(size_t)c*K + k] = f2bf(W[idx]);
}
// tr_temp_w [56512][128] -> WtT [128][56512] bf16 (tiled)
__global__ void k_prepWtT(const float* __restrict__ W, ushort* __restrict__ WT)
{
    __shared__ ushort tile[128][129];
    int k0 = blockIdx.x * 128;
    int t = threadIdx.x;
    for (int i = t; i < 128*128; i += 256) {
        int k = i >> 7, c = i & 127;
        int kk = k0 + k;
        tile[c][k] = (kk < NDM) ? f2bf(W[(size_t)kk*128 + c]) : (ushort)0;
    }
    __syncthreads();
    for (int i = t; i < 128*128; i += 256) {
        int c = i >> 7, k = i & 127;
        int kk = k0 + k;
        if (kk < NDM) WT[(size_t)c*NDM + kk] = tile[c][k];
    }
}
// inv_temp_w [128][56512] -> WT [56512][128] bf16 (tiled, 64 cols/block)
__global__ void k_prepT_big(const float* __restrict__ W, ushort* __restrict__ WT)
{
    __shared__ float tile[128][65];
    int c0 = blockIdx.x * 64;
    int t = threadIdx.x;
    for (int i = t; i < 128*64; i += 256) {
        int k = i >> 6, ci = i & 63;
        tile[k][ci] = W[(size_t)k*NDM + c0 + ci];
    }
    __syncthreads();
    for (int i = t; i < 64*128; i += 256) {
        int ci = i >> 7, k = i & 127;
        WT[(size_t)(c0 + ci)*128 + k] = f2bf(tile[k][ci]);
    }
}
// bias concat: [b1, zeros]
__global__ void k_bcat(const float* __restrict__ b1, float* __restrict__ dst){
    int i = blockIdx.x*256 + threadIdx.x;
    if (i < 1024) dst[i] = (i < 512) ? b1[i] : 0.f;
}

// ======== MFMA fused extractor stage2 (R3 depth-1, (256,3) — best measured 117.3us) =====
// Session conclusion: gather path is request-rate-ceiling bound — occupancy 2/3.3/5.2
// waves-SIMD all land at the same per-row time (R1/R2/R11); target-sort (R3) was the one
// real lever (-20%). 4 blocks/CU thrashes L2 (R11: WRITE_SIZE x4).
template<bool SWZ>
__launch_bounds__(256, 3)
__global__ void ext2_mfma(const ushort* __restrict__ PQ, const ushort* __restrict__ W2T,
                          const float* __restrict__ b2, const float* __restrict__ w3,
                          const float* __restrict__ b3p, const int* __restrict__ ei,
                          const int* __restrict__ lst,
                          float* __restrict__ att, int E, int NN, int nblk)
{
    __shared__ ushort Bs[2][128*40];
    int bid = blockIdx.x;
    if (SWZ) {
        bid = (blockIdx.x & 7) * (gridDim.x >> 3) + (blockIdx.x >> 3);
        if (bid >= nblk) bid = nblk - 1;
    }
    const int t = threadIdx.x;
    const int wv = t >> 6, l = t & 63;
    const int lr = l & 15, lk = l >> 4;

    const ushort* pr[2]; const ushort* qr[2];
    int row0[2];
    #pragma unroll
    for (int rt = 0; rt < 2; ++rt) {
        row0[rt] = bid*128 + wv*32 + rt*16;
        int r = row0[rt] + lr;
        int b = (int)((unsigned)r / (unsigned)E), i = r - b*E;
        int e = lst[i];                      // CSR position -> edge id (target-sorted)
        pr[rt] = PQ + ((size_t)b*NN + ei[e])*1024 + lk*8;
        qr[rt] = PQ + ((size_t)b*NN + ei[E+e])*1024 + 512 + lk*8;
    }
    // B staging: thread t owns col t>>1, 16-ushort half (t&1)
    const int sc = t >> 1, sh = (t & 1) * 16;
    const ushort* wsrc = W2T + (size_t)sc*512 + sh;
    ushort* wd0 = &Bs[0][sc*40 + sh];
    ushort* wd1 = &Bs[1][sc*40 + sh];

    // prologue: B(0)->LDS[0]; A(0)->regs (first, shallow wait at kc=0 repack); B(1)->regs
    {
        int4 a0 = *(const int4*)(wsrc);
        int4 a1 = *(const int4*)(wsrc + 8);
        *(int4*)wd0 = a0;
        *(int4*)(wd0 + 8) = a1;
    }
    HF8 pu[2], qu[2];
    #pragma unroll
    for (int rt = 0; rt < 2; ++rt) {
        pu[rt].i = *(const int4*)(pr[rt]);
        qu[rt].i = *(const int4*)(qr[rt]);
    }
    int4 bnA = *(const int4*)(wsrc + 32);
    int4 bnB = *(const int4*)(wsrc + 40);
    __syncthreads();

    f32x4 acc[2][8] = {};
    for (int kc = 0; kc < 16; ++kc) {
        const int cb = kc & 1;
        // repack A(kc): relu(P+Q) in packed f16, 2 VALU per dword
        HF8 af[2];
        #pragma unroll
        for (int rt = 0; rt < 2; ++rt)
            #pragma unroll
            for (int j = 0; j < 4; ++j)
                af[rt].w[j] = pkrelu(pkaddh(pu[rt].w[j], qu[rt].w[j]));
        // issue next A-gathers FIRST (deep latency, consumed at kc+1 repack)
        {
            int ka = (kc+1 < 15) ? kc+1 : 15;
            #pragma unroll
            for (int rt = 0; rt < 2; ++rt) {
                pu[rt].i = *(const int4*)(pr[rt] + ka*32);
                qu[rt].i = *(const int4*)(qr[rt] + ka*32);
            }
        }
        // MFMA on LDS[cb] — gather latency hides under this cluster
        __builtin_amdgcn_s_setprio(1);
        #pragma unroll
        for (int ct = 0; ct < 8; ++ct) {
            HF8 bfm;
            bfm.v = *(const f16x8*)&Bs[cb][(ct*16 + lr)*40 + lk*8];
            #pragma unroll
            for (int rt = 0; rt < 2; ++rt)
                acc[rt][ct] = __builtin_amdgcn_mfma_f32_16x16x32_f16(af[rt].v, bfm.v,
                                                                    acc[rt][ct], 0, 0, 0);
        }
        __builtin_amdgcn_s_setprio(0);
        // stage B(kc+1) (regs loaded at kc-1), then reload B(kc+2) LAST
        if (kc < 15) {
            ushort* wd = cb ? wd0 : wd1;
            *(int4*)wd = bnA;
            *(int4*)(wd + 8) = bnB;
        }
        {
            int kb = (kc+2 < 15) ? kc+2 : 15;
            bnA = *(const int4*)(wsrc + kb*32);
            bnB = *(const int4*)(wsrc + kb*32 + 8);
        }
        __syncthreads();
    }
    float b3 = b3p[0];
    #pragma unroll
    for (int rt = 0; rt < 2; ++rt) {
        float part[4] = {0.f,0.f,0.f,0.f};
        #pragma unroll
        for (int ct = 0; ct < 8; ++ct) {
            int c = ct*16 + lr;
            float b2v = b2[c], w3v = w3[c];
            #pragma unroll
            for (int g = 0; g < 4; ++g)
                part[g] += fmaxf(acc[rt][ct][g] + b2v, 0.f) * w3v;
        }
        #pragma unroll
        for (int m = 1; m < 16; m <<= 1)
            #pragma unroll
            for (int g = 0; g < 4; ++g)
                part[g] += __shfl_xor(part[g], m, 64);
        if (lr == 0) {
            #pragma unroll
            for (int g = 0; g < 4; ++g) {
                int rr = row0[rt] + lk*4 + g;
                int b = (int)((unsigned)rr / (unsigned)E), i = rr - b*E;
                int e = lst[i];
                att[(size_t)b*E + e] = 1.f/(1.f + expf(-(part[g] + b3)));
            }
        }
    }
}

// ============================ misc ============================
__global__ void k_bias_fill(float* __restrict__ dst, const float* __restrict__ bias, int n){
    int i = blockIdx.x*256 + threadIdx.x;
    if (i < n) dst[i] = bias[i & 127];
}
__global__ void k_f2b(const float* __restrict__ src, ushort* __restrict__ dst, int n){
    int i = blockIdx.x*256 + threadIdx.x;
    if (i < n) dst[i] = f2bf(src[i]);
}

// ============================ hid concat (fp32 + bf16 shadow) ============================
__global__ void k_hid(const float* __restrict__ ts_res, const float* __restrict__ ts_temp,
                      const float* __restrict__ node_emb, const float* __restrict__ tid_emb,
                      const float* __restrict__ diw_emb, const float* __restrict__ hist,
                      float* __restrict__ hid, ushort* __restrict__ hidB)
{
    int idx = blockIdx.x*256 + threadIdx.x;
    if (idx >= RBN*320) return;
    int r = idx / 320, c = idx - r*320;
    int b = r / N_, n = r - b*N_;
    float v;
    if (c < 64)        v = ts_res[(size_t)r*64 + c];
    else if (c < 128)  v = ts_temp[(size_t)r*64 + (c-64)];
    else if (c < 192)  v = node_emb[(size_t)n*64 + (c-128)];
    else if (c < 256) {
        int tid = (int)hist[((size_t)(b*L_ + (L_-1))*N_ + n)*3 + 1];
        v = tid_emb[(size_t)tid*64 + (c-192)];
    } else {
        int diw = (int)hist[((size_t)(b*L_ + (L_-1))*N_ + n)*3 + 2];
        v = diw_emb[(size_t)diw*64 + (c-256)];
    }
    hid[idx] = v;
    hidB[idx] = f2bf(v);
}

// =====================================================================================
extern "C" void kernel_launch(void* const* d_in, const int* in_sizes, int n_in,
                              void* d_out, int out_size, void* d_ws, size_t ws_size,
                              hipStream_t stream)
{
    (void)in_sizes; (void)n_in; (void)out_size; (void)ws_size;
    const float* hist      = (const float*)d_in[0];
    const int*   ei_sp     = (const int*)  d_in[1];
    const int*   ei_tp     = (const int*)  d_in[2];
    const float* node_emb  = (const float*)d_in[3];
    const float* tid_emb   = (const float*)d_in[4];
    const float* diw_emb   = (const float*)d_in[5];
    const float* start_w   = (const float*)d_in[6];
    const float* start_b   = (const float*)d_in[7];
    const float* ts_w      = (const float*)d_in[8];
    const float* ts_b      = (const float*)d_in[9];
    const float* tr_spat_w = (const float*)d_in[10];
    const float* tr_spat_b = (const float*)d_in[11];
    const float* inv_spat_w= (const float*)d_in[12];
    const float* inv_spat_b= (const float*)d_in[13];
    const float* tr_temp_w = (const float*)d_in[14];
    const float* tr_temp_b = (const float*)d_in[15];
    const float* inv_temp_w= (const float*)d_in[16];
    const float* inv_temp_b= (const float*)d_in[17];
    const float* gat_sp_w  = (const float*)d_in[18];
    const float* gat_sp_as = (const float*)d_in[19];
    const float* gat_sp_ad = (const float*)d_in[20];
    const float* gat_sp_b  = (const float*)d_in[21];
    const float* ext_sp_w1 = (const float*)d_in[22];
    const float* ext_sp_b1 = (const float*)d_in[23];
    const float* ext_sp_w2 = (const float*)d_in[24];
    const float* ext_sp_b2 = (const float*)d_in[25];
    const float* ext_sp_w3 = (const float*)d_in[26];
    const float* ext_sp_b3 = (const float*)d_in[27];
    const float* gat_tp_w  = (const float*)d_in[28];
    const float* gat_tp_as = (const float*)d_in[29];
    const float* gat_tp_ad = (const float*)d_in[30];
    const float* gat_tp_b  = (const float*)d_in[31];
    const float* ext_tp_w1 = (const float*)d_in[32];
    const float* ext_tp_b1 = (const float*)d_in[33];
    const float* ext_tp_w2 = (const float*)d_in[34];
    const float* ext_tp_b2 = (const float*)d_in[35];
    const float* ext_tp_w3 = (const float*)d_in[36];
    const float* ext_tp_b3 = (const float*)d_in[37];
    const float* enc_w1    = (const float*)d_in[38];
    const float* enc_b1    = (const float*)d_in[39];
    const float* enc_w2    = (const float*)d_in[40];
    const float* enc_b2    = (const float*)d_in[41];
    const float* reg_w     = (const float*)d_in[42];
    const float* reg_b     = (const float*)d_in[43];
    float* out = (float*)d_out;

    // ---------------- workspace layout (byte-granular, 256B aligned) ----------------
    size_t o = 0;
    char* wsb = (char*)d_ws;
    auto allocB = [&](size_t bytes) -> void* {
        void* p = wsb + o;
        o += (bytes + 255) & ~(size_t)255;
        return p;
    };
    // big reusable arenas
    void* bufA = allocB((size_t)RBN*768*2);   // hid fp32[RBN][320]
    void* bufB = allocB((size_t)RBN*768*2);   // PQ_sp[RBN][1024]f16 (spills into bufC)
    void* bufC = allocB((size_t)RBN*512*2);   // (PQ_sp tail) -> hidB[RBN][320]bf16
    void* bufD = allocB((size_t)RBN*320*2);   // R1b (encoder temp bf16)
    float*  ts_res  = (float*)allocB((size_t)RBN*64*4);
    ushort* spaB    = (ushort*)allocB((size_t)RBN*128*2);  // spa_in -> spa_out
    ushort* hB      = (ushort*)allocB((size_t)RBN*128*2);  // h_sp -> h_tp
    float*  sc_s    = (float*)allocB((size_t)RBN*4*4);
    float*  sc_d    = (float*)allocB((size_t)RBN*4*4);
    float*  att     = (float*)allocB((size_t)B_*E_SP*4);
    ushort* embB    = (ushort*)allocB((size_t)RBN*128*2);
    int*    csr     = (int*)allocB(17024*4);
    float*  temp_in = (float*)allocB((size_t)RBL*128*4);
    ushort* tempB   = (ushort*)allocB((size_t)RBL*128*2);
    ushort* toutB   = (ushort*)allocB((size_t)RBL*128*2);
    ushort* PQ_t    = (ushort*)allocB((size_t)RBL*1024*2);
    float*  ts_temp = (float*)allocB((size_t)RBN*64*4);
    // weight preps
    ushort* W2T_sp  = (ushort*)allocB(512*128*2);
    ushort* W2T_tp  = (ushort*)allocB(512*128*2);
    ushort* WtT     = (ushort*)allocB((size_t)128*NDM*2);   // tr_temp_w^T
    ushort* itWT    = (ushort*)allocB((size_t)NDM*128*2);   // inv_temp_w^T
    ushort* ispWT   = (ushort*)allocB(768*128*2);           // inv_spat_w^T
    ushort* gspWT   = (ushort*)allocB(128*128*2);
    ushort* gtpWT   = (ushort*)allocB(128*128*2);
    ushort* w1catT_sp = (ushort*)allocB((size_t)1024*128*2);
    ushort* w1catT_tp = (ushort*)allocB((size_t)1024*128*2);
    float*  b1cat_sp  = (float*)allocB(1024*4);
    float*  b1cat_tp  = (float*)allocB(1024*4);
    ushort* w1T_enc = (ushort*)allocB((size_t)3*320*320*2);
    ushort* w2T_enc = (ushort*)allocB((size_t)3*320*320*2);
    ushort* tswT_hi = (ushort*)allocB(64*768*2);
    ushort* reg_wT  = (ushort*)allocB(16*320*2);
    float*  A1      = (float*)allocB(36*64*4);
    float*  A2      = (float*)allocB(36*128*4);
    float*  cb1     = (float*)allocB(64*4);
    float*  cb2     = (float*)allocB(128*4);

    float*  hid   = (float*)bufA;     // [RBN][320] fp32
    ushort* PQ_sp = (ushort*)bufB;    // [RBN][1024] f16 (57.9 MB, spans bufB+bufC)
    ushort* hidB  = (ushort*)bufC;
    ushort* R1b   = (ushort*)bufD;

    int* counts_sp = csr;
    int* off_sp    = csr + 883;
    int* cur_sp    = csr + 1767;
    int* list_sp   = csr + 2650;
    int* counts_tp = csr + 16778;
    int* off_tp    = csr + 16790;
    int* cur_tp    = csr + 16803;
    int* list_tp   = csr + 16815;

    // ---------------- CSR builds + weight prep ----------------
    hipMemsetAsync(counts_sp, 0, 883*4, stream);
    k_count<<<cdiv_h(E_SP,256),256,0,stream>>>(ei_sp, E_SP, counts_sp);
    k_scan<<<1,1024,0,stream>>>(counts_sp, off_sp, cur_sp, 883);
    k_fill<<<cdiv_h(E_SP,256),256,0,stream>>>(ei_sp, E_SP, cur_sp, list_sp);
    hipMemsetAsync(counts_tp, 0, 12*4, stream);
    k_count<<<1,256,0,stream>>>(ei_tp, E_TP, counts_tp);
    k_scan<<<1,1024,0,stream>>>(counts_tp, off_tp, cur_tp, 12);
    k_fill<<<1,256,0,stream>>>(ei_tp, E_TP, cur_tp, list_tp);
    k_mkA<<<cdiv_h(36*64+36*128+192,256),256,0,stream>>>(start_w, start_b, ts_w, ts_b,
                                                         tr_spat_w, tr_spat_b,
                                                         A1, A2, cb1, cb2);
    k_prepW2<<<cdiv_h(512*128,256),256,0,stream>>>(ext_sp_w2, W2T_sp);
    k_prepW2<<<cdiv_h(512*128,256),256,0,stream>>>(ext_tp_w2, W2T_tp);
    k_prepWtT<<<cdiv_h(NDM,128),256,0,stream>>>(tr_temp_w, WtT);
    k_prepT_big<<<NDM/64,256,0,stream>>>(inv_temp_w, itWT);
    k_prepT<<<cdiv_h(128*768,256),256,0,stream>>>(inv_spat_w, ispWT, 128, 768);
    k_prepT<<<cdiv_h(128*128,256),256,0,stream>>>(gat_sp_w, gspWT, 128, 128);
    k_prepT<<<cdiv_h(128*128,256),256,0,stream>>>(gat_tp_w, gtpWT, 128, 128);
    k_prepT<<<cdiv_h(128*512,256),256,0,stream>>>(ext_sp_w1,           w1catT_sp,           128, 512);
    k_prepT<<<cdiv_h(128*512,256),256,0,stream>>>(ext_sp_w1 + 128*512, w1catT_sp + 512*128, 128, 512);
    k_prepT<<<cdiv_h(128*512,256),256,0,stream>>>(ext_tp_w1,           w1catT_tp,           128, 512);
    k_prepT<<<cdiv_h(128*512,256),256,0,stream>>>(ext_tp_w1 + 128*512, w1catT_tp + 512*128, 128, 512);
    k_bcat<<<4,256,0,stream>>>(ext_sp_b1, b1cat_sp);
    k_bcat<<<4,256,0,stream>>>(ext_tp_b1, b1cat_tp);
    for (int i = 0; i < 3; ++i) {
        k_prepT<<<cdiv_h(320*320,256),256,0,stream>>>(enc_w1 + (size_t)i*320*320, w1T_enc + (size_t)i*320*320, 320, 320);
        k_prepT<<<cdiv_h(320*320,256),256,0,stream>>>(enc_w2 + (size_t)i*320*320, w2T_enc + (size_t)i*320*320, 320, 320);
    }
    k_prepT<<<cdiv_h(768*64,256),256,0,stream>>>(ts_w, tswT_hi, 768, 64);
    hipMemsetAsync(reg_wT, 0, 16*320*2, stream);
    k_prepT<<<cdiv_h(320*12,256),256,0,stream>>>(reg_w, reg_wT, 320, 12);

    // ---------------- fused front chain: ts_res (fp32) + spa_in (bf16) from hist ----------
    k_front<<<cdiv_h(RBN*192,256),256,0,stream>>>(hist, A1, A2, cb1, cb2, ts_res, spaB);

    // ---------------- spatial GAT ----------------
    mgemm_rt<2,4,0,false,false><<<dim3(2,221),256,0,stream>>>(spaB, gspWT, nullptr, nullptr,
                                                              hB, RBN, 128, 128);
    k_sc<<<cdiv_h(RBN,16),256,0,stream>>>(hB, gat_sp_as, gat_sp_ad, sc_s, sc_d, RBN);
    k_gather<false><<<RBN/4,256,0,stream>>>(hB, sc_s, sc_d, nullptr, ei_sp, off_sp, list_sp,
                                            gat_sp_b, embB, E_SP, N_);
    // extractor: PQ = emb@[W1a|W1b] + [b1|0] (f16); att = sigmoid(MLP) via f16 MFMA
    mgemm_rt<2,8,4,false,false><<<dim3(8,221),256,0,stream>>>(embB, w1catT_sp, b1cat_sp, nullptr,
                                                              PQ_sp, RBN, 1024, 128);
    ext2_mfma<true><<<3536,256,0,stream>>>(PQ_sp, W2T_sp, ext_sp_b2, ext_sp_w3, ext_sp_b3,
                                           ei_sp, list_sp, att, E_SP, N_, (B_*E_SP)/128);
    k_gather<true><<<RBN/4,256,0,stream>>>(hB, sc_s, sc_d, att, ei_sp, off_sp, list_sp,
                                           gat_sp_b, spaB, E_SP, N_);

    // ---------------- fused spatial back-projection + temporal input ----------------
    k_bias_fill<<<cdiv_h(RBL*128,256),256,0,stream>>>(temp_in, tr_temp_b, RBL*128);
    k_tempIn<<<dim3(cdiv_h(N_,TNC),2),256,0,stream>>>(spaB, ispWT, inv_spat_b, WtT, temp_in);
    k_f2b<<<cdiv_h(RBL*128,256),256,0,stream>>>(temp_in, tempB, RBL*128);

    // ---------------- temporal GAT ----------------
    mgemm_rt<2,4,0,false,false><<<dim3(2,3),256,0,stream>>>(tempB, gtpWT, nullptr, nullptr,
                                                            hB, RBL, 128, 128);
    k_sc<<<cdiv_h(RBL,16),256,0,stream>>>(hB, gat_tp_as, gat_tp_ad, sc_s, sc_d, RBL);
    k_gather<false><<<RBL/4,256,0,stream>>>(hB, sc_s, sc_d, nullptr, ei_tp, off_tp, list_tp,
                                            gat_tp_b, embB, E_TP, NT_);
    mgemm_rt<2,8,4,false,false><<<dim3(8,3),256,0,stream>>>(embB, w1catT_tp, b1cat_tp, nullptr,
                                                            PQ_t, RBL, 1024, 128);
    ext2_mfma<false><<<(B_*E_TP)/128,256,0,stream>>>(PQ_t, W2T_tp, ext_tp_b2, ext_tp_w3,
                                                     ext_tp_b3, ei_tp, list_tp, att, E_TP, NT_,
                                                     (B_*E_TP)/128);
    k_gather<true><<<RBL/4,256,0,stream>>>(hB, sc_s, sc_d, att, ei_tp, off_tp, list_tp,
                                           gat_tp_b, toutB, E_TP, NT_);

    // ---------------- fused temporal back-projection + ts_temp ----------------
    k_tsTemp<<<N_,256,0,stream>>>(toutB, itWT, inv_temp_b, tswT_hi, ts_b, ts_temp);

    // ---------------- concat + residual MLP encoder (R8 proven form) + head ---------
    k_hid<<<cdiv_h(RBN*320,256),256,0,stream>>>(ts_res, ts_temp, node_emb, tid_emb, diw_emb, hist,
                                                hid, hidB);
    for (int i = 0; i < 3; ++i) {
        mgemm_rt<2,5,0,true,false><<<dim3(4,221),256,0,stream>>>(hidB, w1T_enc + (size_t)i*320*320,
                                                                 enc_b1 + i*320, nullptr, R1b, RBN, 320, 320);
        mgemm_rt<2,5,0,false,true><<<dim3(4,221),256,0,stream>>>(R1b, w2T_enc + (size_t)i*320*320,
                                                                 enc_b2 + i*320, hid, hidB, RBN, 320, 320);
    }
    mgemm<1,0,2,false,false><<<dim3(1,442),256,0,stream>>>(hidB, reg_wT, reg_b, nullptr,
                                                           out, RBN, 16, 320);
}